// Round 11
// baseline (114.845 us; speedup 1.0000x reference)
//
#include <hip/hip_runtime.h>

#define N_NODES 50000
#define N_PAD   50048        // padded (xb pad rows incl. zero row; cursor pad)
#define N_EDGES 600000
#define IN_F 128
#define HID 256
#define OUT_F 64
#define ROWS 16              // nodes per block; 50000/16 = 3125 blocks exactly
#define SLOTS 56             // fixed bucket slots/node; P(deg>=56|Poisson(12))~1e-24
#define GBLK (N_NODES / ROWS)
#define ZERO_ROW N_NODES     // xb row 50000 is zeroed; padded gather slots read it

typedef __attribute__((ext_vector_type(8))) short bf16x8;
typedef __attribute__((ext_vector_type(4))) float f32x4;

__device__ inline short f2bf(float f) {   // RNE float->bf16 bits
    unsigned u = __builtin_bit_cast(unsigned, f);
    u += 0x7fffu + ((u >> 16) & 1u);
    return (short)(u >> 16);
}
__device__ inline float bflo(unsigned u) { return __builtin_bit_cast(float, u << 16); }
__device__ inline float bfhi(unsigned u) { return __builtin_bit_cast(float, u & 0xffff0000u); }

// ---------------------------------------------------------------------------
// prep: convert x -> bf16, weights -> bf16 B-fragment-major chunks, zero
// cursor, zero the xb pad rows (incl. ZERO_ROW used for gather padding).
//   [0,3125)      x fp32 -> bf16
//   [3125,3173)   12288 weight chunks: F1a, F1b, Fc (= bf16(Wsg@W2a), fp32
//                 inline GEMM), F2b
//   [3173,3200)   zero cursor
//   [3200,3203)   zero xb rows 50000..50047 (768 16B chunks)
// chunk c: lane=c&63, ks=(c>>6)%KST, nt=(c>>6)/KST;
//   elem j: B[ks*32 + (lane>>4)*8 + j][nt*16 + (lane&15)]
// ---------------------------------------------------------------------------
__global__ __launch_bounds__(256) void prep_kernel(
    const float* __restrict__ x, short* __restrict__ xb,
    const float* __restrict__ Wsg, const float* __restrict__ W2a,
    const float* __restrict__ W1a, const float* __restrict__ W1b,
    const float* __restrict__ W2b,
    short* __restrict__ F1a, short* __restrict__ F1b,
    short* __restrict__ Fc,  short* __restrict__ F2b,
    int* __restrict__ cursor)
{
    const int bid = blockIdx.x, t = threadIdx.x;
    if (bid < 3125) {
        int i = bid * 256 + t;                       // < 800000 exactly
        float4 a0 = *reinterpret_cast<const float4*>(x + (size_t)i * 8);
        float4 a1 = *reinterpret_cast<const float4*>(x + (size_t)i * 8 + 4);
        bf16x8 v;
        v[0] = f2bf(a0.x); v[1] = f2bf(a0.y); v[2] = f2bf(a0.z); v[3] = f2bf(a0.w);
        v[4] = f2bf(a1.x); v[5] = f2bf(a1.y); v[6] = f2bf(a1.z); v[7] = f2bf(a1.w);
        *reinterpret_cast<bf16x8*>(xb + (size_t)i * 8) = v;
        return;
    }
    if (bid >= 3200) {
        int i = (bid - 3200) * 256 + t;              // < 768 exactly
        bf16x8 z = {0, 0, 0, 0, 0, 0, 0, 0};
        *reinterpret_cast<bf16x8*>(xb + (size_t)N_NODES * IN_F + (size_t)i * 8) = z;
        return;
    }
    if (bid >= 3173) {
        for (int i = (bid - 3173) * 256 + t; i < N_PAD; i += 27 * 256)
            cursor[i] = 0;
        return;
    }
    int cid = (bid - 3125) * 256 + t;                // < 12288 exactly
    if (cid >= 6144 && cid < 10240) {
        // Fc chunk: Wc = Wsg @ W2a computed in fp32, then bf16 fragment
        int c = cid - 6144;
        int lane = c & 63, rem = c >> 6;
        int ks = rem & 3, nt = rem >> 2;
        int col = nt * 16 + (lane & 15);
        int k0 = ks * 32 + (lane >> 4) * 8;
        float acc[8] = {0.f, 0.f, 0.f, 0.f, 0.f, 0.f, 0.f, 0.f};
        for (int m0 = 0; m0 < 128; m0 += 8) {
            float wcol[8];
            #pragma unroll
            for (int mm = 0; mm < 8; ++mm)
                wcol[mm] = W2a[(size_t)(m0 + mm) * HID + col];
            #pragma unroll
            for (int j = 0; j < 8; ++j) {
                #pragma unroll
                for (int mm = 0; mm < 8; ++mm)
                    acc[j] = fmaf(Wsg[(size_t)(k0 + j) * IN_F + m0 + mm], wcol[mm], acc[j]);
            }
        }
        bf16x8 v;
        #pragma unroll
        for (int j = 0; j < 8; ++j) v[j] = f2bf(acc[j]);
        *reinterpret_cast<bf16x8*>(Fc + (size_t)c * 8) = v;
    } else {
        const float* src; short* dst; int N, KST, base;
        if      (cid < 4096)  { src = W1a; dst = F1a; N = 256; KST = 4; base = 0; }
        else if (cid < 6144)  { src = W1b; dst = F1b; N = 64;  KST = 8; base = 4096; }
        else                  { src = W2b; dst = F2b; N = 64;  KST = 8; base = 10240; }
        int c = cid - base;
        int lane = c & 63;
        int rem = c >> 6;
        int ks = rem % KST;
        int nt = rem / KST;
        int col = nt * 16 + (lane & 15);
        int k0 = ks * 32 + (lane >> 4) * 8;
        bf16x8 v;
        #pragma unroll
        for (int j = 0; j < 8; ++j)
            v[j] = f2bf(src[(size_t)(k0 + j) * N + col]);
        *reinterpret_cast<bf16x8*>(dst + (size_t)c * 8) = v;
    }
}

// ---------------------------------------------------------------------------
// build: fixed-stride bucket fill, 1 edge/thread (max TLP for latency-bound
// atomics). Runs alone (round-7 lesson: merging with streams costs 2-3x).
// cursor (zeroed by prep) ends up as deg.
// ---------------------------------------------------------------------------
__global__ __launch_bounds__(256) void build_kernel(
    const int* __restrict__ ei, int* __restrict__ cursor,
    unsigned short* __restrict__ esrc)
{
    int e = blockIdx.x * 256 + threadIdx.x;
    if (e >= N_EDGES) return;
    int src = ei[e];
    int dst = ei[N_EDGES + e];
    int p = atomicAdd(&cursor[dst], 1);
    if (p < SLOTS) esrc[(size_t)dst * SLOTS + p] = (unsigned short)src;
}

// ---------------------------------------------------------------------------
// gather: standalone mean-aggregation. No LDS, no MFMA registers -> max
// residency for the latency-bound phase (round-10 diagnosis: gather inside
// the fused kernel ran at ~3 waves/CU effective).
// Writes bf16 mean rows to mb — which ALIASES d_out byte-exactly
// (row r: 128 bf16 = 256 B = out row r's 64 fp32). Kernel boundary
// syncs all writes before mlp reads.
// ---------------------------------------------------------------------------
__global__ __launch_bounds__(256) void gather_kernel(
    const short* __restrict__ xb, const unsigned short* __restrict__ esrc,
    const int* __restrict__ deg, short* __restrict__ mb)
{
    const int t = threadIdx.x, w = t >> 6, lane = t & 63;
    const long r0 = (long)blockIdx.x * ROWS;

    #pragma unroll
    for (int nn = 0; nn < 4; ++nn) {
        long node = r0 + w * 4 + nn;                 // < 50000 always
        int d = min(deg[node], SLOTS);
        int du = __builtin_amdgcn_readfirstlane(d);  // wave-uniform
        int slot = min(lane, SLOTS - 1);
        int my = esrc[(size_t)node * SLOTS + slot];  // coalesced 2B/lane
        float ax = 0.f, ay = 0.f;
        for (int j = 0; j < du; j += 16) {
            unsigned u[16];
            #pragma unroll
            for (int k = 0; k < 16; ++k) {
                int idx = j + k;
                int s = (idx < du) ? __builtin_amdgcn_readlane(my, idx)
                                   : ZERO_ROW;       // SALU cselect; zero row
                u[k] = *reinterpret_cast<const unsigned*>(
                    xb + (size_t)s * IN_F + lane * 2);
            }
            #pragma unroll
            for (int k = 0; k < 16; ++k) {
                ax += bflo(u[k]);                    // padded rows add 0
                ay += bfhi(u[k]);
            }
        }
        float inv = (du > 0) ? 1.0f / (float)du : 0.0f;
        ax *= inv; ay *= inv;
        unsigned packed = (unsigned)(unsigned short)f2bf(ax)
                        | ((unsigned)(unsigned short)f2bf(ay) << 16);
        *reinterpret_cast<unsigned*>(mb + node * IN_F + lane * 2) = packed;
    }
}

// ---------------------------------------------------------------------------
// LDS helper for the 16x256 Hs tiles (16B-chunk XOR swizzle)
// ---------------------------------------------------------------------------
__device__ inline bf16x8 afrag_lds256(const short* S, int lane, int ks) {
    int row = lane & 15, g = lane >> 4;
    int chunk = (ks * 4 + g) ^ row;
    return *reinterpret_cast<const bf16x8*>(
        reinterpret_cast<const char*>(S) + row * 512 + chunk * 16);
}

// ---------------------------------------------------------------------------
// mlp: ONE barrier. afrA from xb (global), afrB from mb (global, aliases out).
//   dual stage1: Hs1 = relu(x@W1a+b1a) || Hs2 = relu(mean@Wc+b2a)   sync
//   dual stage2: o1 += Hs1@W1b || o2 += Hs2@W2b
//   out = o1 + o2 + b1b + b2b
// Per block: mb reads (rows r0..r0+15) happen before out writes (same rows,
// same bytes) — data-dependent through the MFMA chain. Blocks touch disjoint
// row ranges. NOTE: mb/out deliberately NOT __restrict__ (they alias).
// ---------------------------------------------------------------------------
__global__ __launch_bounds__(256) void mlp_kernel(
    const short* __restrict__ xb, const short* mb,
    const short* __restrict__ F1a, const float* __restrict__ b1a,
    const short* __restrict__ F1b, const float* __restrict__ b1b,
    const short* __restrict__ Fc,  const float* __restrict__ b2a,
    const short* __restrict__ F2b, const float* __restrict__ b2b,
    float* out)
{
    __shared__ short Hs1[16 * 256];   // 8 KB
    __shared__ short Hs2[16 * 256];   // 8 KB
    const int t = threadIdx.x, w = t >> 6, lane = t & 63;
    const long r0 = (long)blockIdx.x * ROWS;
    const int row16 = lane & 15, g = lane >> 4;

    // ---- A-frags: both operands straight from global, issued back-to-back ----
    bf16x8 afrA[4], afrB[4];
    {
        const short* xrow = xb + (size_t)(r0 + row16) * IN_F + g * 8;
        const short* mrow = mb + (size_t)(r0 + row16) * IN_F + g * 8;
        #pragma unroll
        for (int ks = 0; ks < 4; ++ks) {
            afrA[ks] = *reinterpret_cast<const bf16x8*>(xrow + ks * 32);
            afrB[ks] = *reinterpret_cast<const bf16x8*>(mrow + ks * 32);
        }
    }

    // ---- dual stage1: two independent MFMA chains per nt ----
    #pragma unroll
    for (int i = 0; i < 4; ++i) {
        int nt = w * 4 + i;
        bf16x8 bA[4], bB[4];
        #pragma unroll
        for (int ks = 0; ks < 4; ++ks) {
            bA[ks] = *reinterpret_cast<const bf16x8*>(
                F1a + ((size_t)(nt * 4 + ks) * 64 + lane) * 8);
            bB[ks] = *reinterpret_cast<const bf16x8*>(
                Fc + ((size_t)(nt * 4 + ks) * 64 + lane) * 8);
        }
        f32x4 acc1 = {0.f, 0.f, 0.f, 0.f};
        f32x4 acc2 = {0.f, 0.f, 0.f, 0.f};
        #pragma unroll
        for (int ks = 0; ks < 4; ++ks) {
            acc1 = __builtin_amdgcn_mfma_f32_16x16x32_bf16(afrA[ks], bA[ks], acc1, 0, 0, 0);
            acc2 = __builtin_amdgcn_mfma_f32_16x16x32_bf16(afrB[ks], bB[ks], acc2, 0, 0, 0);
        }
        int col = nt * 16 + row16;
        float bias1 = b1a[col], bias2 = b2a[col];
        #pragma unroll
        for (int reg = 0; reg < 4; ++reg) {
            int hrow = g * 4 + reg;
            int off = hrow * 512 + ((((col >> 3) ^ hrow) & 31) * 16) + (col & 7) * 2;
            *reinterpret_cast<short*>(reinterpret_cast<char*>(Hs1) + off)
                = f2bf(fmaxf(acc1[reg] + bias1, 0.0f));
            *reinterpret_cast<short*>(reinterpret_cast<char*>(Hs2) + off)
                = f2bf(fmaxf(acc2[reg] + bias2, 0.0f));
        }
    }
    __syncthreads();

    // ---- dual stage2 + single store (no tail: 3125 blocks cover exactly) ----
    f32x4 o1 = {0.f, 0.f, 0.f, 0.f};
    f32x4 o2 = {0.f, 0.f, 0.f, 0.f};
    #pragma unroll
    for (int ks = 0; ks < 8; ++ks) {
        bf16x8 a1 = afrag_lds256(Hs1, lane, ks);
        bf16x8 b1 = *reinterpret_cast<const bf16x8*>(
            F1b + ((size_t)(w * 8 + ks) * 64 + lane) * 8);
        o1 = __builtin_amdgcn_mfma_f32_16x16x32_bf16(a1, b1, o1, 0, 0, 0);
        bf16x8 a2 = afrag_lds256(Hs2, lane, ks);
        bf16x8 b2 = *reinterpret_cast<const bf16x8*>(
            F2b + ((size_t)(w * 8 + ks) * 64 + lane) * 8);
        o2 = __builtin_amdgcn_mfma_f32_16x16x32_bf16(a2, b2, o2, 0, 0, 0);
    }
    {
        int col = w * 16 + row16;
        float bias = b1b[col] + b2b[col];
        #pragma unroll
        for (int reg = 0; reg < 4; ++reg) {
            long row = r0 + g * 4 + reg;
            out[row * OUT_F + col] = o1[reg] + o2[reg] + bias;
        }
    }
}

// ---------------------------------------------------------------------------
extern "C" void kernel_launch(void* const* d_in, const int* in_sizes, int n_in,
                              void* d_out, int out_size, void* d_ws, size_t ws_size,
                              hipStream_t stream)
{
    const float* x   = (const float*)d_in[0];
    const int*   ei  = (const int*)d_in[1];
    const float* Wsg = (const float*)d_in[2];
    const float* W1a = (const float*)d_in[3];
    const float* b1a = (const float*)d_in[4];
    const float* W1b = (const float*)d_in[5];
    const float* b1b = (const float*)d_in[6];
    const float* W2a = (const float*)d_in[7];
    const float* b2a = (const float*)d_in[8];
    const float* W2b = (const float*)d_in[9];
    const float* b2b = (const float*)d_in[10];
    float* out = (float*)d_out;
    short* mb  = (short*)d_out;     // bf16 mean rows alias out byte-exactly

    // workspace layout (all 16B-aligned): ~18.8 MB total
    int* cursor = (int*)d_ws;                              // [N_PAD] (200 KB)
    unsigned short* esrc = (unsigned short*)(cursor + N_PAD);  // [N_PAD*56] = 5.6 MB
    short* F1a = (short*)(esrc + (size_t)N_PAD * SLOTS);   // 4096 chunks (64 KB)
    short* F1b = F1a + 4096 * 8;                           // 2048 chunks (32 KB)
    short* Fc  = F1b + 2048 * 8;                           // 4096 chunks (64 KB)
    short* F2b = Fc + 4096 * 8;                            // 2048 chunks (32 KB)
    short* xb  = F2b + 2048 * 8;                           // [N_PAD*128] bf16 (12.8 MB)

    prep_kernel<<<3203, 256, 0, stream>>>(x, xb, Wsg, W2a, W1a, W1b, W2b,
                                          F1a, F1b, Fc, F2b, cursor);
    build_kernel<<<(N_EDGES + 255) / 256, 256, 0, stream>>>(ei, cursor, esrc);
    gather_kernel<<<GBLK, 256, 0, stream>>>(xb, esrc, cursor, mb);
    mlp_kernel<<<GBLK, 256, 0, stream>>>(xb, mb,
                                         F1a, b1a, F1b, b1b,
                                         Fc, b2a, F2b, b2b, out);
}